// Round 1
// 1149.919 us; speedup vs baseline: 1.2478x; 1.2478x over previous
//
#include <hip/hip_runtime.h>

#define BB 16
#define CC 32
#define KK 4
#define CKD 128     // C*K
#define NN 8192
#define NLEV 13
#define AL 128      // ALPHA (weight mode-axis storage stride)
#define PMAX 6      // max K-split for fwd DFT

struct LevTab { int off[NLEV]; int n[NLEV]; int l[NLEV]; int total; };
struct MixTab2 { long long off[NLEV]; int l[NLEV]; int mcum[NLEV]; };

// tw [j][m] and twT [m][j]; value = (cos,sin)(2*pi*((j*m) mod n)/n)
__global__ void twiddle_fill_k(float2* __restrict__ tw, float2* __restrict__ twT, LevTab t) {
  int idx = blockIdx.x * blockDim.x + threadIdx.x;
  if (idx >= t.total) return;
  int lev = 0;
  for (int q = 1; q < NLEV; q++) lev = (idx >= t.off[q]) ? q : lev;
  int r = idx - t.off[lev];
  int n = t.n[lev], l = t.l[lev];
  int j = r / l, m = r - j * l;
  long long pp = ((long long)j * (long long)m) % n;
  float ang = (float)((double)pp * (6.283185307179586476925286766559 / (double)n));
  float s, c;
  sincosf(ang, &s, &c);
  float2 v = make_float2(c, s);
  tw[t.off[lev] + j * l + m] = v;
  twT[t.off[lev] + m * n + j] = v;
}

// x:(B,2n,C,K) -> s:(B,n,C,K), d:(B,n,C,K)
__global__ void decompose_k(const float* __restrict__ xin, float* __restrict__ sout,
                            float* __restrict__ dout,
                            const float* __restrict__ ecs, const float* __restrict__ ecd,
                            int nh) {
  int idx = blockIdx.x * blockDim.x + threadIdx.x;
  if (idx >= BB * nh * CC) return;
  int c = idx & (CC - 1);
  int t = idx / CC;
  int j = t % nh;
  int b = t / nh;
  size_t ib = (((size_t)b * (2 * nh) + 2 * j) * CC + c) * KK;
  float4 xe = *(const float4*)(xin + ib);
  float4 xo = *(const float4*)(xin + ib + CC * KK);
  float xa[8] = {xe.x, xe.y, xe.z, xe.w, xo.x, xo.y, xo.z, xo.w};
  float sv[4] = {0.f,0.f,0.f,0.f}, dv[4] = {0.f,0.f,0.f,0.f};
  #pragma unroll
  for (int p = 0; p < 8; p++) {
    float v = xa[p];
    #pragma unroll
    for (int k = 0; k < 4; k++) {
      sv[k] = fmaf(v, ecs[p*4+k], sv[k]);
      dv[k] = fmaf(v, ecd[p*4+k], dv[k]);
    }
  }
  size_t ob = (((size_t)b * nh + j) * CC + c) * KK;
  *(float4*)(sout + ob) = make_float4(sv[0], sv[1], sv[2], sv[3]);
  *(float4*)(dout + ob) = make_float4(dv[0], dv[1], dv[2], dv[3]);
}

// ---- tiled forward DFT: Xf[b,i,m] = sum_j v[b,j,i]*(cos,-sin)(jm) ----
// block 256 = 16tx(m) x 16ty(i); tile 64i x 64m; K = j chunked 16, split P ways.
// grid: x = ceil(l/64), y = b*2+itile, z = srcs*P + ks
__global__ void fwd_dft_t(const float* __restrict__ dsrc, const float* __restrict__ ssrc,
                          float2* __restrict__ Dp, float2* __restrict__ Sp,
                          const float2* __restrict__ tw, int n, int l, int P, int chunk) {
  __shared__ float As[16][64];
  __shared__ float Bc[16][64];
  __shared__ float Bn[16][64];
  int zz = blockIdx.z;
  int srcs = (zz >= P) ? 1 : 0;
  int ks = zz - srcs * P;
  const float* __restrict__ src = srcs ? ssrc : dsrc;
  size_t spcl = (size_t)BB * CKD * l;
  float2* __restrict__ dst = (srcs ? Sp : Dp) + (size_t)ks * spcl;
  int m0 = blockIdx.x << 6;
  int by = blockIdx.y;
  int it = by & 1, b = by >> 1;
  int i0 = it << 6;
  int tid = threadIdx.x;
  int tx = tid & 15, ty = tid >> 4;
  int k_start = ks * chunk;
  int k_cnt = n - k_start;
  if (k_cnt > chunk) k_cnt = chunk;
  float are[4][4], aim[4][4];
  #pragma unroll
  for (int a = 0; a < 4; a++)
    #pragma unroll
    for (int d = 0; d < 4; d++) { are[a][d] = 0.f; aim[a][d] = 0.f; }

  for (int j0 = 0; j0 < k_cnt; j0 += 16) {
    { // stage A: 16 j-rows x 64 i floats
      int row = tid >> 4;
      int c4 = (tid & 15) << 2;
      float4 v = make_float4(0.f,0.f,0.f,0.f);
      if (j0 + row < k_cnt) {
        int jg = k_start + j0 + row;
        v = *(const float4*)(src + ((size_t)b * n + jg) * CKD + i0 + c4);
      }
      *(float4*)&As[row][c4] = v;
    }
    #pragma unroll
    for (int it2 = 0; it2 < 2; it2++) { // stage twiddles into cos/sin planes
      int idx = tid + (it2 << 8);
      int row = idx >> 5;
      int cm = (idx & 31) << 1;
      float4 v = make_float4(0.f,0.f,0.f,0.f);
      if (j0 + row < k_cnt) {
        int jg = k_start + j0 + row;
        int mg = m0 + cm;
        if (mg + 1 < l) v = *(const float4*)(tw + (size_t)jg * l + mg);
        else if (mg < l) { float2 t2 = tw[(size_t)jg * l + mg]; v.x = t2.x; v.y = t2.y; }
      }
      Bc[row][cm] = v.x;  Bn[row][cm] = v.y;
      Bc[row][cm+1] = v.z; Bn[row][cm+1] = v.w;
    }
    __syncthreads();
    #pragma unroll
    for (int j = 0; j < 16; j++) {
      float av[4], cr[4], ci[4];
      *(float4*)av = *(const float4*)&As[j][ty << 2];
      *(float4*)cr = *(const float4*)&Bc[j][tx << 2];
      *(float4*)ci = *(const float4*)&Bn[j][tx << 2];
      #pragma unroll
      for (int ii = 0; ii < 4; ii++)
        #pragma unroll
        for (int mm = 0; mm < 4; mm++) {
          are[ii][mm] = fmaf(av[ii],  cr[mm], are[ii][mm]);
          aim[ii][mm] = fmaf(av[ii], -ci[mm], aim[ii][mm]);
        }
    }
    __syncthreads();
  }
  #pragma unroll
  for (int ii = 0; ii < 4; ii++) {
    int i = i0 + (ty << 2) + ii;
    #pragma unroll
    for (int mm = 0; mm < 4; mm++) {
      int m = m0 + (tx << 2) + mm;
      if (m < l) dst[((size_t)b * CKD + i) * l + m] = make_float2(are[ii][mm], aim[ii][mm]);
    }
  }
}

// sum P partial spectra (scratch) into compact Dall/Sall slots
__global__ void reduce_k(float4* __restrict__ dD, float4* __restrict__ dS,
                         const float4* __restrict__ pD, const float4* __restrict__ pS,
                         int cnt4, int P) {
  int idx = blockIdx.x * blockDim.x + threadIdx.x;
  if (idx >= 2 * cnt4) return;
  const float4* src = (idx < cnt4) ? pD : pS;
  float4* dst = (idx < cnt4) ? dD : dS;
  int e = (idx < cnt4) ? idx : idx - cnt4;
  float4 a = src[e];
  for (int p = 1; p < P; p++) {
    float4 v = src[(size_t)p * cnt4 + e];
    a.x += v.x; a.y += v.y; a.z += v.z; a.w += v.w;
  }
  dst[e] = a;
}

// weight transpose: W[i][o][m] (re,im separate) -> Wt[m][i][o] interleaved float2
// grid (i=CKD, ochunk=4, tensor=3), block 256
__global__ void wtr_k(const float* __restrict__ Ar, const float* __restrict__ Ai,
                      const float* __restrict__ Br, const float* __restrict__ Bi,
                      const float* __restrict__ Cr, const float* __restrict__ Ci,
                      float2* __restrict__ WtA, float2* __restrict__ WtB,
                      float2* __restrict__ WtC) {
  __shared__ float2 Ts[32][130];   // padded: load-phase bank spread
  int i = blockIdx.x;
  int o0 = blockIdx.y << 5;
  int z = blockIdx.z;
  const float* Wr = (z == 0) ? Ar : ((z == 1) ? Br : Cr);
  const float* Wi = (z == 0) ? Ai : ((z == 1) ? Bi : Ci);
  float2* Wt = (z == 0) ? WtA : ((z == 1) ? WtB : WtC);
  int tid = threadIdx.x;
  { // load 32 o x 128 m, coalesced over m
    int o = tid >> 3, m0 = (tid & 7) << 4;
    const float* rp = Wr + ((size_t)i * CKD + o0 + o) * AL + m0;
    const float* ip = Wi + ((size_t)i * CKD + o0 + o) * AL + m0;
    #pragma unroll
    for (int r = 0; r < 4; r++) {
      float4 vr = *(const float4*)(rp + r * 4);
      float4 vi = *(const float4*)(ip + r * 4);
      Ts[o][m0 + r*4 + 0] = make_float2(vr.x, vi.x);
      Ts[o][m0 + r*4 + 1] = make_float2(vr.y, vi.y);
      Ts[o][m0 + r*4 + 2] = make_float2(vr.z, vi.z);
      Ts[o][m0 + r*4 + 3] = make_float2(vr.w, vi.w);
    }
  }
  __syncthreads();
  { // store 128 m x 32 o, coalesced over o
    int m = tid >> 1, oh = (tid & 1) << 4;
    float2* wp = Wt + ((size_t)m * CKD + i) * CKD + o0 + oh;
    #pragma unroll
    for (int r = 0; r < 16; r += 2) {
      float2 e0 = Ts[oh + r][m];
      float2 e1 = Ts[oh + r + 1][m];
      *(float4*)(wp + r) = make_float4(e0.x, e0.y, e1.x, e1.y);
    }
  }
}

// batched per-(lev,m) complex GEMM: U[b,o] = sum_i D[b,i]*A[i,o] + S[b,i]*B[i,o]
//                                   V[b,o] = sum_i D[b,i]*C[i,o]
// grid.x = sum_q l_q (774); block 256 = 128 o-lanes x 2 b-halves (8 b each)
__global__ void __launch_bounds__(256)
mix2_k(const float2* __restrict__ Dall, const float2* __restrict__ Sall,
       const float2* __restrict__ WA, const float2* __restrict__ WB,
       const float2* __restrict__ WC,
       float2* __restrict__ Uall, float2* __restrict__ Vall, MixTab2 mt) {
  __shared__ __align__(16) float2 Dl[CKD][BB];
  __shared__ __align__(16) float2 Sl[CKD][BB];
  int bx = blockIdx.x;
  int lev = 0;
  #pragma unroll
  for (int q = 1; q < NLEV; q++) lev = (bx >= mt.mcum[q]) ? q : lev;
  int m = bx - mt.mcum[lev];
  int l = mt.l[lev];
  const float2* __restrict__ D = Dall + mt.off[lev];
  const float2* __restrict__ S = Sall + mt.off[lev];
  float2* __restrict__ U = Uall + mt.off[lev];
  float2* __restrict__ V = Vall + mt.off[lev];
  int tid = threadIdx.x;
  int o = tid & (CKD - 1), bh = tid >> 7;
  { // stage D,S slice for this mode into LDS as [i][b]
    int b = tid & 15, i0 = (tid >> 4) << 3;
    #pragma unroll
    for (int r = 0; r < 8; r++) {
      int i = i0 + r;
      size_t g = ((size_t)b * CKD + i) * l + m;
      Dl[i][b] = D[g];
      Sl[i][b] = S[g];
    }
  }
  __syncthreads();
  float ur[8], ui[8], vr[8], vi[8];
  #pragma unroll
  for (int r = 0; r < 8; r++) { ur[r] = 0.f; ui[r] = 0.f; vr[r] = 0.f; vi[r] = 0.f; }
  const float2* wa = WA + (size_t)m * CKD * CKD + o;
  const float2* wb = WB + (size_t)m * CKD * CKD + o;
  const float2* wc = WC + (size_t)m * CKD * CKD + o;
  #pragma unroll 4
  for (int i = 0; i < CKD; i++) {
    float2 a  = wa[(size_t)i * CKD];
    float2 bw = wb[(size_t)i * CKD];
    float2 cw = wc[(size_t)i * CKD];
    float2 dv[8], sv[8];
    #pragma unroll
    for (int r = 0; r < 4; r++) {
      *(float4*)&dv[r*2] = *(const float4*)&Dl[i][(bh << 3) + r*2];
      *(float4*)&sv[r*2] = *(const float4*)&Sl[i][(bh << 3) + r*2];
    }
    #pragma unroll
    for (int r = 0; r < 8; r++) {
      float2 d = dv[r], s = sv[r];
      ur[r] = fmaf(d.x, a.x, ur[r]);  ur[r] = fmaf(-d.y, a.y, ur[r]);
      ur[r] = fmaf(s.x, bw.x, ur[r]); ur[r] = fmaf(-s.y, bw.y, ur[r]);
      ui[r] = fmaf(d.x, a.y, ui[r]);  ui[r] = fmaf(d.y, a.x, ui[r]);
      ui[r] = fmaf(s.x, bw.y, ui[r]); ui[r] = fmaf(s.y, bw.x, ui[r]);
      vr[r] = fmaf(d.x, cw.x, vr[r]); vr[r] = fmaf(-d.y, cw.y, vr[r]);
      vi[r] = fmaf(d.x, cw.y, vi[r]); vi[r] = fmaf(d.y, cw.x, vi[r]);
    }
  }
  #pragma unroll
  for (int r = 0; r < 8; r++) {
    int b = (bh << 3) + r;
    size_t ob = ((size_t)b * l + m) * CKD + o;
    U[ob] = make_float2(ur[r], ui[r]);
    V[ob] = make_float2(vr[r], vi[r]);
  }
}

// ---- tiled inverse DFT ----
// y[b,j,o] = (2*sum_{m=0..l-1}(Gr*cos - Gi*sin) - G0.re - nyq*(-1)^j*G[l-1].re)/n
__global__ void inv_dft_t(const float2* __restrict__ Uf, const float2* __restrict__ Vf,
                          float* __restrict__ ud, float* __restrict__ us,
                          const float2* __restrict__ twT, int n, int l, int nyq) {
  __shared__ float Gr[16][64];
  __shared__ float Gi[16][64];
  __shared__ float2 Ts[16][64];
  int z = blockIdx.z;
  const float2* __restrict__ G = (z ? Vf : Uf);
  float* __restrict__ out = (z ? us : ud);
  int j0 = blockIdx.x << 6;
  int by = blockIdx.y;
  int ot = by & 1, b = by >> 1;
  int o0 = ot << 6;
  int tid = threadIdx.x;
  int tx = tid & 15, ty = tid >> 4;
  float acc[4][4];
  #pragma unroll
  for (int a = 0; a < 4; a++)
    #pragma unroll
    for (int d = 0; d < 4; d++) acc[a][d] = 0.f;

  for (int m0 = 0; m0 < l; m0 += 16) {
    #pragma unroll
    for (int it2 = 0; it2 < 2; it2++) { // stage G into re/im planes
      int idx = tid + (it2 << 8);
      int row = idx >> 5;
      int co = (idx & 31) << 1;
      float4 v = make_float4(0.f,0.f,0.f,0.f);
      if (m0 + row < l)
        v = *(const float4*)(G + ((size_t)b * l + m0 + row) * CKD + o0 + co);
      Gr[row][co] = v.x;   Gi[row][co] = v.y;
      Gr[row][co+1] = v.z; Gi[row][co+1] = v.w;
    }
    #pragma unroll
    for (int it2 = 0; it2 < 2; it2++) { // stage twT tile
      int idx = tid + (it2 << 8);
      int row = idx >> 5;
      int cj = (idx & 31) << 1;
      float4 v = make_float4(0.f,0.f,0.f,0.f);
      if (m0 + row < l) {
        int jg = j0 + cj;
        if (jg + 1 < n) v = *(const float4*)(twT + (size_t)(m0 + row) * n + jg);
        else if (jg < n) { float2 t2 = twT[(size_t)(m0 + row) * n + jg]; v.x = t2.x; v.y = t2.y; }
      }
      *(float4*)&Ts[row][cj] = v;
    }
    __syncthreads();
    #pragma unroll
    for (int mm = 0; mm < 16; mm++) {
      float gr[4], gi[4];
      float2 cs[4];
      *(float4*)gr = *(const float4*)&Gr[mm][tx << 2];
      *(float4*)gi = *(const float4*)&Gi[mm][tx << 2];
      *(float4*)&cs[0] = *(const float4*)&Ts[mm][ty << 2];
      *(float4*)&cs[2] = *(const float4*)&Ts[mm][(ty << 2) + 2];
      #pragma unroll
      for (int jj = 0; jj < 4; jj++)
        #pragma unroll
        for (int oo = 0; oo < 4; oo++) {
          acc[jj][oo] = fmaf(gr[oo],  cs[jj].x, acc[jj][oo]);
          acc[jj][oo] = fmaf(gi[oo], -cs[jj].y, acc[jj][oo]);
        }
    }
    __syncthreads();
  }
  float invn = 1.f / (float)n;
  float g0[4], gn[4];
  #pragma unroll
  for (int oo = 0; oo < 4; oo++) {
    int o = o0 + (tx << 2) + oo;
    g0[oo] = G[((size_t)b * l) * CKD + o].x;
    gn[oo] = nyq ? G[((size_t)b * l + (l - 1)) * CKD + o].x : 0.f;
  }
  #pragma unroll
  for (int jj = 0; jj < 4; jj++) {
    int j = j0 + (ty << 2) + jj;
    if (j < n) {
      float sgn = (j & 1) ? -1.f : 1.f;
      float4 y;
      float* yp = &y.x;
      #pragma unroll
      for (int oo = 0; oo < 4; oo++)
        yp[oo] = (2.f * acc[jj][oo] - g0[oo] - sgn * gn[oo]) * invn;
      *(float4*)(out + ((size_t)b * n + j) * CKD + o0 + (tx << 2)) = y;
    }
  }
}

// coarsest map: y = x @ T0_w^T + T0_b
__global__ void t0_k(const float* __restrict__ xin, const float* __restrict__ w,
                     const float* __restrict__ bv, float* __restrict__ xout) {
  int idx = blockIdx.x * blockDim.x + threadIdx.x;
  if (idx >= BB * CC * KK) return;
  int k = idx & 3;
  int bc = idx >> 2;
  float a = bv[k];
  #pragma unroll
  for (int kp = 0; kp < 4; kp++) a = fmaf(xin[bc*4 + kp], w[k*4 + kp], a);
  xout[idx] = a;
}

__global__ void recon_k(const float* __restrict__ xin, const float* __restrict__ usl,
                        const float* __restrict__ udl,
                        const float* __restrict__ rce, const float* __restrict__ rco,
                        float* __restrict__ xout, int nh) {
  int idx = blockIdx.x * blockDim.x + threadIdx.x;
  if (idx >= BB * nh * CC) return;
  int c = idx & (CC - 1);
  int t = idx / CC;
  int j = t % nh;
  int b = t / nh;
  size_t ib = (((size_t)b * nh + j) * CC + c) * KK;
  float4 xv = *(const float4*)(xin + ib);
  float4 uv = *(const float4*)(usl + ib);
  float4 dv = *(const float4*)(udl + ib);
  float xx[8] = {xv.x+uv.x, xv.y+uv.y, xv.z+uv.z, xv.w+uv.w, dv.x, dv.y, dv.z, dv.w};
  float ev[4] = {0.f,0.f,0.f,0.f}, ov[4] = {0.f,0.f,0.f,0.f};
  #pragma unroll
  for (int p = 0; p < 8; p++) {
    float v = xx[p];
    #pragma unroll
    for (int k = 0; k < 4; k++) {
      ev[k] = fmaf(v, rce[p*4+k], ev[k]);
      ov[k] = fmaf(v, rco[p*4+k], ov[k]);
    }
  }
  size_t ob = (((size_t)b * (2*nh) + 2*j) * CC + c) * KK;
  *(float4*)(xout + ob) = make_float4(ev[0], ev[1], ev[2], ev[3]);
  *(float4*)(xout + ob + CC*KK) = make_float4(ov[0], ov[1], ov[2], ov[3]);
}

extern "C" void kernel_launch(void* const* d_in, const int* in_sizes, int n_in,
                              void* d_out, int out_size, void* d_ws, size_t ws_size,
                              hipStream_t stream) {
  const float* x   = (const float*)d_in[0];
  const float* wAr = (const float*)d_in[1];
  const float* wAi = (const float*)d_in[2];
  const float* wBr = (const float*)d_in[3];
  const float* wBi = (const float*)d_in[4];
  const float* wCr = (const float*)d_in[5];
  const float* wCi = (const float*)d_in[6];
  const float *ecs, *ecd, *rce, *rco, *t0w, *t0b;
  if (in_sizes[7] == 16) {
    t0w = (const float*)d_in[7];  t0b = (const float*)d_in[8];
    ecs = (const float*)d_in[9];  ecd = (const float*)d_in[10];
    rce = (const float*)d_in[11]; rco = (const float*)d_in[12];
  } else {
    ecs = (const float*)d_in[7];  ecd = (const float*)d_in[8];
    rce = (const float*)d_in[9];  rco = (const float*)d_in[10];
    t0w = (const float*)d_in[11]; t0b = (const float*)d_in[12];
  }

  int nh[NLEV], lv[NLEV];
  size_t twoff[NLEV], spoff[NLEV];   // spoff in float2 units within Dall/Sall/Uall/Vall
  size_t tacc = 0, spacc = 0;
  for (int q = 0; q < NLEV; q++) {
    nh[q] = NN >> (q + 1);
    int li = nh[q] / 2 + 1;
    lv[q] = li < AL ? li : AL;
    twoff[q] = tacc; tacc += (size_t)nh[q] * lv[q];
    spoff[q] = spacc; spacc += (size_t)BB * CKD * lv[q];
  }

  float* ws = (float*)d_ws;
  const size_t XS = (size_t)BB * (NN/2) * CKD;     // 8,388,608 floats
  float*  xb0  = ws;                               // XS floats
  float*  xb1  = xb0 + XS;                         // XS/2 floats (recon q=1 spills into Dall: dead then)
  float2* Dall = (float2*)(xb1 + XS / 2);          // spacc float2
  float2* Sall = Dall + spacc;
  float2* Uall = Sall + spacc;                     // also fwd partial scratch (dead until mix)
  float2* Vall = Uall + spacc;
  float*  udT  = (float*)(Vall + spacc);           // XS floats (also stages d per level; Wt home)
  float*  usT  = udT + XS;                         // XS floats
  float2* tw   = (float2*)(usT + XS);
  float2* twT  = tw + tacc;
  float2* scrD = Uall;                             // fwd partials: up to PMAX * 262144 float2
  float2* scrS = Uall + (size_t)PMAX * BB * CKD * AL;
  // transposed weights live in udT..usT (dead between decompose and reconstruct):
  // 3 tensors x 128^3 float2 = 50.3 MB <= 67.1 MB
  float2* WtA = (float2*)udT;
  float2* WtB = WtA + (size_t)CKD * CKD * AL;
  float2* WtC = WtB + (size_t)CKD * CKD * AL;

  LevTab lt;
  for (int q = 0; q < NLEV; q++) { lt.off[q] = (int)twoff[q]; lt.n[q] = nh[q]; lt.l[q] = lv[q]; }
  lt.total = (int)tacc;
  twiddle_fill_k<<<dim3((unsigned)((tacc + 255) / 256)), 256, 0, stream>>>(tw, twT, lt);

  // ---------- decompose + forward DFT (all levels) ----------
  const float* cur = x;
  float* nxt = xb0;
  for (int q = 0; q < NLEV; q++) {
    int n2 = nh[q], l = lv[q];
    float* dtmp = udT;                 // transient d staging
    int tot = BB * n2 * CC;
    decompose_k<<<dim3((tot + 255) / 256), 256, 0, stream>>>(cur, nxt, dtmp, ecs, ecd, n2);

    int P = n2 / 128; if (P < 1) P = 1; if (P > PMAX) P = PMAX;
    int chunk = (((n2 + P - 1) / P) + 15) & ~15;
    float2* Dp = (P > 1) ? scrD : (Dall + spoff[q]);
    float2* Sp = (P > 1) ? scrS : (Sall + spoff[q]);
    fwd_dft_t<<<dim3((l + 63) / 64, BB * 2, 2 * P), 256, 0, stream>>>(dtmp, nxt, Dp, Sp,
                                                                      tw + twoff[q], n2, l,
                                                                      P, chunk);
    if (P > 1) {
      int cnt4 = (BB * CKD * l) / 2;   // float4 per partial
      reduce_k<<<dim3((2 * cnt4 + 255) / 256), 256, 0, stream>>>(
          (float4*)(Dall + spoff[q]), (float4*)(Sall + spoff[q]),
          (const float4*)scrD, (const float4*)scrS, cnt4, P);
    }
    cur = nxt;
    nxt = (nxt == xb0) ? xb1 : xb0;
  }

  // ---------- transpose weights into [m][i][o] float2 ----------
  wtr_k<<<dim3(CKD, 4, 3), 256, 0, stream>>>(wAr, wAi, wBr, wBi, wCr, wCi, WtA, WtB, WtC);

  // ---------- batched per-(lev,m) complex GEMM mode-mix ----------
  MixTab2 mt;
  int mc = 0;
  for (int q = 0; q < NLEV; q++) {
    mt.off[q] = (long long)spoff[q];
    mt.l[q] = lv[q];
    mt.mcum[q] = mc;
    mc += lv[q];
  }
  mix2_k<<<dim3((unsigned)mc), 256, 0, stream>>>(Dall, Sall, WtA, WtB, WtC, Uall, Vall, mt);

  // ---------- coarsest linear map ----------
  // cur holds s12 (in xb0 after 13 alternations); write t0 out to the other buffer
  float* t0out = (cur == xb0) ? xb1 : xb0;
  t0_k<<<dim3((BB * CC * KK + 255) / 256), 256, 0, stream>>>(cur, t0w, t0b, t0out);

  // ---------- reconstruct (inverse DFT deferred per level) ----------
  const float* rcur = t0out;
  float* rnxt = (t0out == xb0) ? xb1 : xb0;
  for (int q = NLEV - 1; q >= 0; q--) {
    int n2 = nh[q], l = lv[q];
    int nyq = (((n2 & 1) == 0) && (l == n2 / 2 + 1)) ? 1 : 0;
    inv_dft_t<<<dim3((n2 + 63) / 64, BB * 2, 2), 256, 0, stream>>>(
        Uall + spoff[q], Vall + spoff[q], udT, usT, twT + twoff[q], n2, l, nyq);
    float* outp = (q == 0) ? (float*)d_out : rnxt;
    int tot = BB * n2 * CC;
    recon_k<<<dim3((tot + 255) / 256), 256, 0, stream>>>(rcur, usT, udT,
                                                         rce, rco, outp, n2);
    rcur = outp;
    rnxt = (rnxt == xb0) ? xb1 : xb0;
  }
}